// Round 3
// baseline (146.935 us; speedup 1.0000x reference)
//
#include <hip/hip_runtime.h>
#include <math.h>

#define BB 512
#define SS 200
#define DD 512
#define KK 128
#define RR (BB * SS)   // 102400 rows

typedef __attribute__((ext_vector_type(8))) short bf16x8;
typedef __attribute__((ext_vector_type(4))) float f32x4;

__device__ inline unsigned short f2bf(float f) {
    union { float f; unsigned int u; } v; v.f = f;
    unsigned int r = v.u + 0x7FFFu + ((v.u >> 16) & 1u);   // RNE
    return (unsigned short)(r >> 16);
}

// ---------------------------------------------------------------------------
// Wt[col][d] = bf16(W[d][col])  — 128x512 bf16, done once, L2-resident after
// ---------------------------------------------------------------------------
__global__ void wt_kernel(const float* __restrict__ W, unsigned short* __restrict__ Wt) {
    int i = blockIdx.x * 256 + threadIdx.x;   // over 128*512
    int col = i >> 9, d = i & 511;
    Wt[i] = f2bf(W[d * KK + col]);
}

// ---------------------------------------------------------------------------
// logits[row] = sum_k tanh( A[row,:] . Wt[k,:] ) * wpk[k] + bias[row % SS]
// Double-buffered LDS, T14 issue-early loads, 1 barrier/iter.
// 256 threads (4 waves), 128 rows/block, BK=32.
// ---------------------------------------------------------------------------
__global__ __launch_bounds__(256, 3) void logits_mfma_kernel(
    const float* __restrict__ A,
    const unsigned short* __restrict__ Wt,   // [KK][DD] bf16
    const float* __restrict__ wpk,           // [KK]
    const float* __restrict__ bias,          // [SS]
    float* __restrict__ out)                 // [RR]
{
    __shared__ unsigned short As[2][128][40];
    __shared__ unsigned short Bs[2][128][40];

    int tid = threadIdx.x;
    int w = tid >> 6;
    int l15 = tid & 15;
    int g = (tid & 63) >> 4;
    size_t row0 = (size_t)blockIdx.x * 128;

    f32x4 acc[2][8];
    #pragma unroll
    for (int m = 0; m < 2; ++m)
        #pragma unroll
        for (int n = 0; n < 8; ++n) acc[m][n] = (f32x4){0.f, 0.f, 0.f, 0.f};

    float wv[8];
    #pragma unroll
    for (int n = 0; n < 8; ++n) wv[n] = wpk[n * 16 + l15];

    // staging coords: thread covers (row ar, 16 d-cols at ac) of both tiles
    int ar = tid >> 1;             // 0..127
    int ac = (tid & 1) * 16;       // 0 or 16
    const float*          aptr = A  + (row0 + ar) * DD + ac;
    const unsigned short* bptr = Wt + (size_t)ar * DD + ac;

    float4 sa0, sa1, sa2, sa3;     // staged A (fp32)
    bf16x8 sb0, sb1;               // staged B (bf16)

    #define LOADT(d0) do {                                   \
        const float* s_ = aptr + (d0);                       \
        sa0 = *(const float4*)(s_);                          \
        sa1 = *(const float4*)(s_ + 4);                      \
        sa2 = *(const float4*)(s_ + 8);                      \
        sa3 = *(const float4*)(s_ + 12);                     \
        const unsigned short* t_ = bptr + (d0);              \
        sb0 = *(const bf16x8*)(t_);                          \
        sb1 = *(const bf16x8*)(t_ + 8);                      \
    } while (0)

    #define WRITET(buf) do {                                 \
        bf16x8 p0_, p1_;                                     \
        p0_[0] = (short)f2bf(sa0.x); p0_[1] = (short)f2bf(sa0.y); \
        p0_[2] = (short)f2bf(sa0.z); p0_[3] = (short)f2bf(sa0.w); \
        p0_[4] = (short)f2bf(sa1.x); p0_[5] = (short)f2bf(sa1.y); \
        p0_[6] = (short)f2bf(sa1.z); p0_[7] = (short)f2bf(sa1.w); \
        p1_[0] = (short)f2bf(sa2.x); p1_[1] = (short)f2bf(sa2.y); \
        p1_[2] = (short)f2bf(sa2.z); p1_[3] = (short)f2bf(sa2.w); \
        p1_[4] = (short)f2bf(sa3.x); p1_[5] = (short)f2bf(sa3.y); \
        p1_[6] = (short)f2bf(sa3.z); p1_[7] = (short)f2bf(sa3.w); \
        *(bf16x8*)&As[buf][ar][ac]     = p0_;                \
        *(bf16x8*)&As[buf][ar][ac + 8] = p1_;                \
        *(bf16x8*)&Bs[buf][ar][ac]     = sb0;                \
        *(bf16x8*)&Bs[buf][ar][ac + 8] = sb1;                \
    } while (0)

    LOADT(0);
    WRITET(0);
    __syncthreads();

    for (int t = 0; t < 16; ++t) {
        int p = t & 1;
        if (t < 15) LOADT((t + 1) * 32);   // issue next tile's loads early
        bf16x8 af0 = *(const bf16x8*)&As[p][w * 32 + l15][g * 8];
        bf16x8 af1 = *(const bf16x8*)&As[p][w * 32 + 16 + l15][g * 8];
        #pragma unroll
        for (int n = 0; n < 8; ++n) {
            bf16x8 bf = *(const bf16x8*)&Bs[p][n * 16 + l15][g * 8];
            acc[0][n] = __builtin_amdgcn_mfma_f32_16x16x32_bf16(af0, bf, acc[0][n], 0, 0, 0);
            acc[1][n] = __builtin_amdgcn_mfma_f32_16x16x32_bf16(af1, bf, acc[1][n], 0, 0, 0);
        }
        if (t < 15) WRITET(p ^ 1);         // write other buffer; safe pre-barrier
        __syncthreads();
    }

    // --- epilogue: tanh, weight by wpk, reduce over k (cols) ---
    // C/D layout: col = l&15, row = (l>>4)*4 + r
    float rs[2][4];
    #pragma unroll
    for (int m = 0; m < 2; ++m)
        #pragma unroll
        for (int r = 0; r < 4; ++r) rs[m][r] = 0.f;
    #pragma unroll
    for (int m = 0; m < 2; ++m)
        #pragma unroll
        for (int n = 0; n < 8; ++n)
            #pragma unroll
            for (int r = 0; r < 4; ++r)
                rs[m][r] += tanhf(acc[m][n][r]) * wv[n];

    #pragma unroll
    for (int m = 0; m < 2; ++m)
        #pragma unroll
        for (int r = 0; r < 4; ++r) {
            float v = rs[m][r];
            v += __shfl_xor(v, 1, 64);
            v += __shfl_xor(v, 2, 64);
            v += __shfl_xor(v, 4, 64);
            v += __shfl_xor(v, 8, 64);
            rs[m][r] = v;
        }
    if (l15 == 0) {
        #pragma unroll
        for (int m = 0; m < 2; ++m)
            #pragma unroll
            for (int r = 0; r < 4; ++r) {
                int grow = (int)row0 + w * 32 + m * 16 + g * 4 + r;
                out[grow] = rs[m][r] + bias[grow % SS];
            }
    }
}

// ---------------------------------------------------------------------------
// Pt = softmax(logits[b,:]); out[b,s,:] = Pt[s] * tfh[b,s,:]
// ---------------------------------------------------------------------------
__global__ __launch_bounds__(1024) void softmax_mul_kernel(
    const float* __restrict__ logits,
    const float* __restrict__ tfh,
    float* __restrict__ out)
{
    int b = blockIdx.x;
    int tid = threadIdx.x;
    __shared__ float Pt[SS];
    __shared__ float wpart[16];

    float v = (tid < SS) ? logits[(size_t)b * SS + tid] : -INFINITY;
    float m = v;
    #pragma unroll
    for (int off = 32; off > 0; off >>= 1) m = fmaxf(m, __shfl_xor(m, off, 64));
    if ((tid & 63) == 0) wpart[tid >> 6] = m;
    __syncthreads();
    m = -INFINITY;
    #pragma unroll
    for (int i = 0; i < 16; ++i) m = fmaxf(m, wpart[i]);
    float e = (tid < SS) ? expf(v - m) : 0.f;
    float ssum = e;
    #pragma unroll
    for (int off = 32; off > 0; off >>= 1) ssum += __shfl_xor(ssum, off, 64);
    __syncthreads();   // everyone done reading wpart (max) before overwrite
    if ((tid & 63) == 0) wpart[tid >> 6] = ssum;
    __syncthreads();
    ssum = 0.f;
    #pragma unroll
    for (int i = 0; i < 16; ++i) ssum += wpart[i];
    if (tid < SS) Pt[tid] = e / ssum;
    __syncthreads();

    const float4* src = (const float4*)(tfh + (size_t)b * SS * DD);
    float4*       dst = (float4*)(out + (size_t)b * SS * DD);
    const int n4 = SS * DD / 4;   // 25600, 128 float4 per row
    for (int i = tid; i < n4; i += 1024) {
        float p = Pt[i >> 7];
        float4 x = src[i];
        x.x *= p; x.y *= p; x.z *= p; x.w *= p;
        dst[i] = x;
    }
}

// ---------------------------------------------------------------------------
extern "C" void kernel_launch(void* const* d_in, const int* in_sizes, int n_in,
                              void* d_out, int out_size, void* d_ws, size_t ws_size,
                              hipStream_t stream) {
    const float* tfh   = (const float*)d_in[1];
    const float* wVt1  = (const float*)d_in[7];
    const float* wp1   = (const float*)d_in[8];
    const float* bias1 = (const float*)d_in[9];
    float* out = (float*)d_out;

    // ws layout: Wt bf16 [128*512] (128KB) | logits f32 [RR] (400KB)
    unsigned short* Wt = (unsigned short*)d_ws;
    float* logits = (float*)((char*)d_ws + KK * DD * sizeof(unsigned short));

    wt_kernel<<<KK * DD / 256, 256, 0, stream>>>(wVt1, Wt);
    logits_mfma_kernel<<<RR / 128, 256, 0, stream>>>(tfh, Wt, wp1 + KK, bias1, logits);
    softmax_mul_kernel<<<BB, 1024, 0, stream>>>(logits, tfh, out);
}

// Round 4
// 135.333 us; speedup vs baseline: 1.0857x; 1.0857x over previous
//
#include <hip/hip_runtime.h>
#include <math.h>

#define BB 512
#define SS 200
#define DD 512
#define KK 128

typedef __attribute__((ext_vector_type(8))) short bf16x8;
typedef __attribute__((ext_vector_type(4))) float f32x4;

__device__ inline unsigned short f2bf(float f) {
    union { float f; unsigned int u; } v; v.f = f;
    unsigned int r = v.u + 0x7FFFu + ((v.u >> 16) & 1u);   // RNE
    return (unsigned short)(r >> 16);
}

// ---------------------------------------------------------------------------
// Wt[col][d] = bf16(W[d][col])  — 128x512 bf16, once; L2-resident thereafter
// ---------------------------------------------------------------------------
__global__ void wt_kernel(const float* __restrict__ W, unsigned short* __restrict__ Wt) {
    int i = blockIdx.x * 256 + threadIdx.x;   // over 128*512
    int col = i >> 9, d = i & 511;
    Wt[i] = f2bf(W[d * KK + col]);
}

// ---------------------------------------------------------------------------
// Fused per-b kernel: logits (MFMA GEMM + tanh + weighted k-reduce + bias)
//                     -> softmax over s -> out[s,:] = Pt[s] * tfh[b,s,:]
// 512 threads = 8 waves; wave w owns rows w*32..w*32+31 (rows >= 200 wasted).
// ---------------------------------------------------------------------------
__global__ __launch_bounds__(512, 4) void fused_kernel(
    const float* __restrict__ tfh,           // [BB,SS,DD]
    const unsigned short* __restrict__ Wt,   // [KK][DD] bf16
    const float* __restrict__ wpk,           // [KK]
    const float* __restrict__ bias,          // [SS]
    float* __restrict__ out)                 // [BB,SS,DD]
{
    __shared__ unsigned short As[256][40];
    __shared__ unsigned short Bs[128][40];
    __shared__ float logit_s[256];
    __shared__ float Pt[SS];
    __shared__ float wpart[8];

    int tid = threadIdx.x;
    int w   = tid >> 6;        // wave 0..7
    int l   = tid & 63;
    int l15 = l & 15;
    int g   = l >> 4;
    int b   = blockIdx.x;
    const float* Ab = tfh + (size_t)b * SS * DD;

    f32x4 acc[2][8];
    #pragma unroll
    for (int m = 0; m < 2; ++m)
        #pragma unroll
        for (int n = 0; n < 8; ++n) acc[m][n] = (f32x4){0.f, 0.f, 0.f, 0.f};

    float wv[8];
    #pragma unroll
    for (int n = 0; n < 8; ++n) wv[n] = wpk[n * 16 + l15];

    // staging coords: A tile 256 rows x 32 d (2 halves of 16); rows clamped
    int ar  = tid >> 1;                      // 0..255
    int arc = (ar < SS) ? ar : (SS - 1);     // clamp for load safety
    int ac  = (tid & 1) * 16;
    const float* aptr = Ab + (size_t)arc * DD + ac;
    const unsigned short* bptr = Wt + (size_t)(tid >> 1) * DD + ac;  // tid<256 only

    for (int d0 = 0; d0 < DD; d0 += 32) {
        {   // stage A: fp32 -> bf16
            const float* s_ = aptr + d0;
            float4 v0 = *(const float4*)(s_);
            float4 v1 = *(const float4*)(s_ + 4);
            float4 v2 = *(const float4*)(s_ + 8);
            float4 v3 = *(const float4*)(s_ + 12);
            bf16x8 p0, p1;
            p0[0] = (short)f2bf(v0.x); p0[1] = (short)f2bf(v0.y);
            p0[2] = (short)f2bf(v0.z); p0[3] = (short)f2bf(v0.w);
            p0[4] = (short)f2bf(v1.x); p0[5] = (short)f2bf(v1.y);
            p0[6] = (short)f2bf(v1.z); p0[7] = (short)f2bf(v1.w);
            p1[0] = (short)f2bf(v2.x); p1[1] = (short)f2bf(v2.y);
            p1[2] = (short)f2bf(v2.z); p1[3] = (short)f2bf(v2.w);
            p1[4] = (short)f2bf(v3.x); p1[5] = (short)f2bf(v3.y);
            p1[6] = (short)f2bf(v3.z); p1[7] = (short)f2bf(v3.w);
            *(bf16x8*)&As[ar][ac]     = p0;
            *(bf16x8*)&As[ar][ac + 8] = p1;
        }
        if (tid < 256) {   // stage B (already bf16)
            bf16x8 q0 = *(const bf16x8*)(bptr + d0);
            bf16x8 q1 = *(const bf16x8*)(bptr + d0 + 8);
            *(bf16x8*)&Bs[tid >> 1][ac]     = q0;
            *(bf16x8*)&Bs[tid >> 1][ac + 8] = q1;
        }
        __syncthreads();
        bf16x8 af0 = *(const bf16x8*)&As[w * 32 + l15][g * 8];
        bf16x8 af1 = *(const bf16x8*)&As[w * 32 + 16 + l15][g * 8];
        #pragma unroll
        for (int n = 0; n < 8; ++n) {
            bf16x8 bf = *(const bf16x8*)&Bs[n * 16 + l15][g * 8];
            acc[0][n] = __builtin_amdgcn_mfma_f32_16x16x32_bf16(af0, bf, acc[0][n], 0, 0, 0);
            acc[1][n] = __builtin_amdgcn_mfma_f32_16x16x32_bf16(af1, bf, acc[1][n], 0, 0, 0);
        }
        __syncthreads();
    }

    // --- epilogue: tanh, weight, reduce over k; logits into LDS ---
    float rs[2][4];
    #pragma unroll
    for (int m = 0; m < 2; ++m)
        #pragma unroll
        for (int r = 0; r < 4; ++r) rs[m][r] = 0.f;
    #pragma unroll
    for (int m = 0; m < 2; ++m)
        #pragma unroll
        for (int n = 0; n < 8; ++n)
            #pragma unroll
            for (int r = 0; r < 4; ++r)
                rs[m][r] += tanhf(acc[m][n][r]) * wv[n];
    #pragma unroll
    for (int m = 0; m < 2; ++m)
        #pragma unroll
        for (int r = 0; r < 4; ++r) {
            float v = rs[m][r];
            v += __shfl_xor(v, 1, 64);
            v += __shfl_xor(v, 2, 64);
            v += __shfl_xor(v, 4, 64);
            v += __shfl_xor(v, 8, 64);
            rs[m][r] = v;
        }
    if (l15 == 0) {
        #pragma unroll
        for (int m = 0; m < 2; ++m)
            #pragma unroll
            for (int r = 0; r < 4; ++r) {
                int srow = w * 32 + m * 16 + g * 4 + r;
                if (srow < SS) logit_s[srow] = rs[m][r] + bias[srow];
            }
    }
    __syncthreads();

    // --- softmax over 200 entries (all 512 threads participate) ---
    float v = (tid < SS) ? logit_s[tid] : -INFINITY;
    float m = v;
    #pragma unroll
    for (int off = 32; off > 0; off >>= 1) m = fmaxf(m, __shfl_xor(m, off, 64));
    if (l == 0) wpart[w] = m;
    __syncthreads();
    m = -INFINITY;
    #pragma unroll
    for (int i = 0; i < 8; ++i) m = fmaxf(m, wpart[i]);
    float e = (tid < SS) ? expf(v - m) : 0.f;
    float ssum = e;
    #pragma unroll
    for (int off = 32; off > 0; off >>= 1) ssum += __shfl_xor(ssum, off, 64);
    __syncthreads();   // done reading wpart (max) before overwrite
    if (l == 0) wpart[w] = ssum;
    __syncthreads();
    ssum = 0.f;
    #pragma unroll
    for (int i = 0; i < 8; ++i) ssum += wpart[i];
    if (tid < SS) Pt[tid] = e / ssum;
    __syncthreads();

    // --- phase 3: out[s,:] = Pt[s] * tfh[b,s,:]  (re-read hits L2/L3) ---
    const float4* src = (const float4*)Ab;
    float4*       dst = (float4*)(out + (size_t)b * SS * DD);
    const int n4 = SS * DD / 4;   // 25600; 128 float4 per s-row
    for (int i = tid; i < n4; i += 512) {
        float p = Pt[i >> 7];
        float4 x = src[i];
        x.x *= p; x.y *= p; x.z *= p; x.w *= p;
        dst[i] = x;
    }
}

// ---------------------------------------------------------------------------
extern "C" void kernel_launch(void* const* d_in, const int* in_sizes, int n_in,
                              void* d_out, int out_size, void* d_ws, size_t ws_size,
                              hipStream_t stream) {
    const float* tfh   = (const float*)d_in[1];
    const float* wVt1  = (const float*)d_in[7];
    const float* wp1   = (const float*)d_in[8];
    const float* bias1 = (const float*)d_in[9];
    float* out = (float*)d_out;

    unsigned short* Wt = (unsigned short*)d_ws;   // 128KB

    wt_kernel<<<KK * DD / 256, 256, 0, stream>>>(wVt1, Wt);
    fused_kernel<<<BB, 512, 0, stream>>>(tfh, Wt, wp1 + KK, bias1, out);
}